// Round 19
// baseline (94.837 us; speedup 1.0000x reference)
//
#include <hip/hip_runtime.h>

#define B_   4
#define N_   2048
#define DIM  128
#define NH   8
#define HD   16
#define FFN_ 256
#define LN_EPS 1e-5f
#define BN   (B_*N_)
#define LOG2E 1.44269504f

#if __has_builtin(__builtin_amdgcn_exp2f)
#define EXP2(x) __builtin_amdgcn_exp2f(x)
#else
#define EXP2(x) exp2f(x)
#endif

typedef __bf16 bf16x8 __attribute__((ext_vector_type(8)));
typedef short  s16x8  __attribute__((ext_vector_type(8)));
typedef float  f32x16 __attribute__((ext_vector_type(16)));
typedef unsigned int u32x4 __attribute__((ext_vector_type(4)));

template<class T> struct as_short_vec { using type = s16x8; };

template <class T>
__device__ auto mfma_try(T a, T b, f32x16 c, int)
    -> decltype(__builtin_amdgcn_mfma_f32_32x32x16_bf16(a, b, c, 0, 0, 0)) {
  return __builtin_amdgcn_mfma_f32_32x32x16_bf16(a, b, c, 0, 0, 0);
}
template <class T>
__device__ f32x16 mfma_try(T a, T b, f32x16 c, long) {
  return __builtin_amdgcn_mfma_f32_32x32x16_bf16(
      __builtin_bit_cast(typename as_short_vec<T>::type, a),
      __builtin_bit_cast(typename as_short_vec<T>::type, b), c, 0, 0, 0);
}
__device__ __forceinline__ f32x16 mfma_bf(bf16x8 a, bf16x8 b, f32x16 c) {
  return mfma_try(a, b, c, 0);
}

// ---------------- fused prep: adj bits + weight cast + ones buffer ---------
// (r16 lesson: folding this into the qkv launch regressed — keep separate.)
__global__ __launch_bounds__(256) void k_prep(
    const int* __restrict__ adj,
    const float* __restrict__ W1, const float* __restrict__ W2,
    const float* __restrict__ Wq, const float* __restrict__ Wk,
    const float* __restrict__ Wv, const float* __restrict__ Wo,
    unsigned int* __restrict__ adjbT,
    __bf16* __restrict__ W1t, __bf16* __restrict__ W2t,
    __bf16* __restrict__ Wqt, __bf16* __restrict__ Wkt,
    __bf16* __restrict__ Wvt, __bf16* __restrict__ Wot,
    __bf16* __restrict__ onesb) {
    const int blk = blockIdx.x;
    const int tid = threadIdx.x;
    if (blk < 16384) {
        long long idx = (long long)blk * 256 + tid;
        int v = adj[idx] != 0;
        unsigned long long m = __ballot(v);
        if ((tid & 63) == 0) {
            int q  = (int)(idx >> 11);
            int kc = ((int)idx & 2047) >> 5;   // even; covers kc, kc+1
            adjbT[(size_t)kc * 2048 + q]       = (unsigned)m;
            adjbT[(size_t)(kc + 1) * 2048 + q] = (unsigned)(m >> 32);
        }
    } else {
        const int g = (blk - 16384) * 256 + tid;    // 32768 threads
        {
            int k = g >> 8, n = g & 255;
            W1t[(size_t)n * 128 + k] = (__bf16)W1[(size_t)k * 256 + n];
        }
        {
            int k = g >> 7, n = g & 127;
            W2t[(size_t)n * 256 + k] = (__bf16)W2[(size_t)k * 128 + n];
        }
        if (g < 16384) {
            int k = g >> 7, n = g & 127;
            size_t s = (size_t)k * 128 + n, d = (size_t)n * 128 + k;
            Wqt[d] = (__bf16)(Wq[s] * (0.25f * LOG2E));
            Wkt[d] = (__bf16)Wk[s];
            Wvt[d] = (__bf16)Wv[s];
            Wot[d] = (__bf16)Wo[s];
        }
        if (g < 2080) onesb[g] = (__bf16)1.0f;
    }
}

// ---------------- QKV projection, MFMA, 12 waves (3/SIMD) ----------------
__global__ __launch_bounds__(768) void k_qkv(
    const float* __restrict__ h,
    const __bf16* __restrict__ Wqt, const __bf16* __restrict__ Wkt,
    const __bf16* __restrict__ Wvt,
    __bf16* __restrict__ Qb, __bf16* __restrict__ Kb, __bf16* __restrict__ Vt) {
    const int r0   = blockIdx.x * 32;
    const int tid  = threadIdx.x;
    const int w    = tid >> 6;          // 0..11
    const int mat  = w >> 2;            // 0=Q 1=K 2=V
    const int ct   = w & 3;             // col-tile
    const int lane = tid & 63;
    const int l31  = lane & 31, hi = lane >> 5;

    __shared__ __bf16 Hs[32 * 128];   // XOR-swizzled: byte ^= (row&7)<<4

    if (tid < 512) {
        int row = tid >> 4, u = tid & 15;
        const float* src = h + (size_t)(r0 + row) * DIM + u * 8;
        float4 f0 = *(const float4*)src, f1 = *(const float4*)(src + 4);
        bf16x8 v;
        v[0] = (__bf16)f0.x; v[1] = (__bf16)f0.y; v[2] = (__bf16)f0.z; v[3] = (__bf16)f0.w;
        v[4] = (__bf16)f1.x; v[5] = (__bf16)f1.y; v[6] = (__bf16)f1.z; v[7] = (__bf16)f1.w;
        int byte = (row * 256 + u * 16) ^ ((row & 7) << 4);
        *(bf16x8*)((char*)Hs + byte) = v;
    }
    __syncthreads();

    const __bf16* Wsel = (mat == 0) ? Wqt : ((mat == 1) ? Wkt : Wvt);

    f32x16 a;
    #pragma unroll
    for (int i = 0; i < 16; ++i) a[i] = 0.f;
    #pragma unroll
    for (int kk = 0; kk < 8; ++kk) {
        int byte = (l31 * 256 + kk * 32 + hi * 16) ^ ((l31 & 7) << 4);
        bf16x8 af = *(const bf16x8*)((const char*)Hs + byte);
        a = mfma_bf(af, *(const bf16x8*)(Wsel + (size_t)(ct * 32 + l31) * 128 + kk * 16 + hi * 8), a);
    }

    const int n  = ct * 32 + l31;          // output col 0..127
    const int hh = n >> 4, d = n & 15;
    const int b  = r0 >> 11;
    const int nloc0 = r0 & (N_ - 1);
    if (mat < 2) {
        __bf16* dst = (mat == 0) ? Qb : Kb;
        const size_t qbase = (size_t)(b * NH + hh) * N_;
        #pragma unroll
        for (int r = 0; r < 16; ++r) {
            int mm = (r & 3) + 8 * (r >> 2) + 4 * hi;
            dst[(qbase + nloc0 + mm) * HD + d] = (__bf16)a[r];
        }
    } else {
        const size_t vbase = ((size_t)(b * NH + hh) * HD + d) * N_;
        #pragma unroll
        for (int r = 0; r < 16; ++r) {
            int mm   = (r & 3) + 8 * (r >> 2) + 4 * hi;
            int nloc = nloc0 + mm;
            int gg = (nloc >> 2) & 7;
            int ng = (gg & 4) | ((gg & 1) << 1) | ((gg >> 1) & 1);
            Vt[vbase + ((nloc & ~31) | (ng << 2) | (nloc & 3))] = (__bf16)a[r];
        }
    }
}

// ---------------- masked flash attention, MFMA, fixed-max softmax ----------
// r19: 4 q-tiles (128 q-rows) per block — same K/V registers feed 4 tiles,
// quartering K/V L2 traffic vs the r17 baseline (r18 was 2 tiles: 58->53 µs).
// Grid B*H*(N/128) = 512 blocks x 512 thr; no vfa/vfb prefetch (consumed
// ~400 issue-cycles after load, L2 latency covered); kf+mask prefetch only.
// VGPR budget ~125 vs 128 cap — spill tripwire: dur/WRITE_SIZE regression.
__global__ __launch_bounds__(512, 4) void k_attn(
    const __bf16* __restrict__ Qb, const __bf16* __restrict__ Kb,
    const __bf16* __restrict__ Vt, const unsigned int* __restrict__ adjbT,
    const __bf16* __restrict__ onesb,
    __bf16* __restrict__ AOb) {
    const int bid  = (blockIdx.x & 7) * 64 + (blockIdx.x >> 3);   // XCD chunking
    const int qt   = bid & 15;          // N/128 = 16 q-groups of 128 rows
    const int hh   = (bid >> 4) & 7;
    const int b    = bid >> 7;
    const int kq   = threadIdx.x >> 6;  // wave = K eighth
    const int lane = threadIdx.x & 63;
    const int l31  = lane & 31, hi = lane >> 5;
    const int qb0   = qt * 128 + l31;
    const int kbase = kq * 256;
    const int NT    = 8;                // 8 tiles of 32 keys per eighth

    __shared__ float accL[7][64][36];
    __shared__ uint2 lutM[16];

    if (threadIdx.x < 16) {
        unsigned v = threadIdx.x;
        lutM[v].x = ((v & 1u) ? 0xFFFFu : 0u) | ((v & 2u) ? 0xFFFF0000u : 0u);
        lutM[v].y = ((v & 4u) ? 0xFFFFu : 0u) | ((v & 8u) ? 0xFFFF0000u : 0u);
    }
    __syncthreads();

    const __bf16* Qh = Qb + (size_t)(b * NH + hh) * N_ * HD;
    const __bf16* Kp = Kb + (size_t)(b * NH + hh) * N_ * HD
                          + (size_t)(kbase + l31) * HD + hi * 8;
    const __bf16* Vp = ((l31 < 16)
        ? (Vt + ((size_t)(b * NH + hh) * HD + l31) * N_)
        : onesb) + kbase + hi * 8;
    const unsigned int* wp = adjbT + (size_t)(kq * NT) * 2048 + qb0;

    bf16x8 qf[4];
    #pragma unroll
    for (int j = 0; j < 4; ++j)
        qf[j] = *(const bf16x8*)(Qh + (size_t)(qb0 + j * 32) * HD + hi * 8);

    f32x16 acc0, acc1, acc2, acc3;
    #pragma unroll
    for (int i = 0; i < 16; ++i) { acc0[i] = 0.f; acc1[i] = 0.f; acc2[i] = 0.f; acc3[i] = 0.f; }
    const f32x16 z = {};

    bf16x8 kf = *(const bf16x8*)Kp;
    unsigned int w32[4];
    #pragma unroll
    for (int j = 0; j < 4; ++j) w32[j] = wp[j * 32];

    #pragma unroll
    for (int t = 0; t < NT; ++t) {
        // V loads for this tile (consumed after the exp chains — slack covers L2)
        bf16x8 vfa = *(const bf16x8*)(Vp + t * 32);
        bf16x8 vfb = *(const bf16x8*)(Vp + t * 32 + 16);

        // prefetch next kf + mask words
        bf16x8 kf_n = {};
        unsigned int w32_n[4] = {0, 0, 0, 0};
        if (t + 1 < NT) {
            kf_n = *(const bf16x8*)(Kp + (t + 1) * 32 * HD);
            #pragma unroll
            for (int j = 0; j < 4; ++j)
                w32_n[j] = wp[(size_t)(t + 1) * 2048 + j * 32];
        }

        #pragma unroll
        for (int j = 0; j < 4; ++j) {
            const unsigned ws = w32[j] >> (4 * hi);
            uint2 e0 = lutM[ws & 15u];
            uint2 e1 = lutM[(ws >> 8) & 15u];
            uint2 e2 = lutM[(ws >> 16) & 15u];
            uint2 e3 = lutM[(ws >> 24) & 15u];

            // S^T[k][q] (log2-scaled): D: q = l31, k = (r&3)+8*(r>>2)+4*hi
            f32x16 st = mfma_bf(kf, qf[j], z);

            float p[16];
            #pragma unroll
            for (int r = 0; r < 16; ++r) p[r] = EXP2(st[r]);
            bf16x8 pa, pb;
            #pragma unroll
            for (int r = 0; r < 8; ++r) { pa[r] = (__bf16)p[r]; pb[r] = (__bf16)p[r + 8]; }

            u32x4 mA = {e0.x, e0.y, e1.x, e1.y};
            u32x4 mB = {e2.x, e2.y, e3.x, e3.y};
            pa = __builtin_bit_cast(bf16x8, __builtin_bit_cast(u32x4, pa) & mA);
            pb = __builtin_bit_cast(bf16x8, __builtin_bit_cast(u32x4, pb) & mB);

            // PV; A rows 16..31 read global ones -> acc[8] accumulates sum(p)
            f32x16& acc = (j == 0) ? acc0 : (j == 1) ? acc1 : (j == 2) ? acc2 : acc3;
            acc = mfma_bf(vfa, pa, acc);
            acc = mfma_bf(vfb, pb, acc);
        }

        if (t + 1 < NT) {
            kf = kf_n;
            #pragma unroll
            for (int j = 0; j < 4; ++j) w32[j] = w32_n[j];
        }
    }

    // ---- 8-way split-K merge: pure sums, 4 q-tiles ----
    if (kq != 0) {
        #pragma unroll
        for (int r = 0; r < 9; ++r) {
            accL[kq - 1][lane][r]      = acc0[r];
            accL[kq - 1][lane][9 + r]  = acc1[r];
            accL[kq - 1][lane][18 + r] = acc2[r];
            accL[kq - 1][lane][27 + r] = acc3[r];
        }
    }
    __syncthreads();
    if (kq == 0) {
        #pragma unroll
        for (int j = 0; j < 4; ++j) {
            const f32x16& accj = (j == 0) ? acc0 : (j == 1) ? acc1 : (j == 2) ? acc2 : acc3;
            float tot[9];
            #pragma unroll
            for (int r = 0; r < 9; ++r) {
                float v = accj[r];
                #pragma unroll
                for (int i = 0; i < 7; ++i) v += accL[i][lane][j * 9 + r];
                tot[r] = v;
            }
            float inv = 1.f / tot[8];
            bf16x8 ov;
            #pragma unroll
            for (int r = 0; r < 8; ++r) ov[r] = (__bf16)(tot[r] * inv);
            u32x4 ou = __builtin_bit_cast(u32x4, ov);
            __bf16* op = AOb + ((size_t)(b * N_ + qb0 + j * 32)) * DIM + hh * HD + 4 * hi;
            uint2 x0 = { ou[0], ou[1] }, x1 = { ou[2], ou[3] };
            *(uint2*)op       = x0;
            *(uint2*)(op + 8) = x1;
        }
    }
}

// ------- fused tail: Wo proj + residual + LN1 + FFN + residual + LN2 -------
// (unchanged from r15/r17: 512 thr, split-K Wo/GEMM2, per-wave GEMM1)
__global__ __launch_bounds__(512) void k_tail(
    const __bf16* __restrict__ AOb, const float* __restrict__ h,
    const __bf16* __restrict__ Wot, const float* __restrict__ bo,
    const float* __restrict__ g1, const float* __restrict__ b1ln,
    const __bf16* __restrict__ W1t, const float* __restrict__ b1,
    const __bf16* __restrict__ W2t, const float* __restrict__ b2,
    const float* __restrict__ g2, const float* __restrict__ b2ln,
    float* __restrict__ out) {
    const int r0   = blockIdx.x * 32;
    const int tid  = threadIdx.x;
    const int w    = tid >> 6;          // 0..7
    const int ct   = w & 3;
    const int kh   = w >> 2;
    const int lane = tid & 63;
    const int l31  = lane & 31, hi = lane >> 5;

    __shared__ __bf16 As[32 * 128];
    __shared__ __bf16 Xs[32 * 128];
    __shared__ __bf16 Ts[32 * 256];
    __shared__ float  vv[32][DIM];
    __shared__ float  accT[4][64][16];

    {
        int row = tid >> 4, u = tid & 15;
        bf16x8 v = *(const bf16x8*)(AOb + (size_t)(r0 + row) * DIM + u * 8);
        int byte = (row * 256 + u * 16) ^ ((row & 7) << 4);
        *(bf16x8*)((char*)As + byte) = v;
    }
    __syncthreads();

    // GEMM Wo: split-K (K=128 -> 64 per wave)
    f32x16 acc;
    #pragma unroll
    for (int i = 0; i < 16; ++i) acc[i] = 0.f;
    #pragma unroll
    for (int kk = 0; kk < 4; ++kk) {
        int kkk = kh * 4 + kk;
        int byte = (l31 * 256 + kkk * 32 + hi * 16) ^ ((l31 & 7) << 4);
        bf16x8 a = *(const bf16x8*)((const char*)As + byte);
        acc = mfma_bf(a, *(const bf16x8*)(Wot + (size_t)(ct * 32 + l31) * 128 + kkk * 16 + hi * 8), acc);
    }
    if (kh == 1) {
        #pragma unroll
        for (int r = 0; r < 16; ++r) accT[ct][lane][r] = acc[r];
    }
    __syncthreads();
    if (kh == 0) {
        int n = ct * 32 + l31;
        float bb = bo[n];
        #pragma unroll
        for (int r = 0; r < 16; ++r) {
            int mm = (r & 3) + 8 * (r >> 2) + 4 * hi;
            vv[mm][n] = acc[r] + accT[ct][lane][r] + bb + h[(size_t)(r0 + mm) * DIM + n];
        }
    }
    __syncthreads();

    // LN1 -> Xs (swizzled bf16); 8 waves x 4 rows
    {
        const int ln = lane;
        float gc0 = g1[ln], bc0 = b1ln[ln], gc1 = g1[ln + 64], bc1 = b1ln[ln + 64];
        #pragma unroll
        for (int i = 0; i < 4; ++i) {
            int rr = w * 4 + i;
            float x0 = vv[rr][ln], x1 = vv[rr][ln + 64];
            float s = x0 + x1, s2 = x0 * x0 + x1 * x1;
            for (int off = 1; off < 64; off <<= 1) {
                s  += __shfl_xor(s,  off);
                s2 += __shfl_xor(s2, off);
            }
            float mu  = s * (1.f / DIM);
            float var = s2 * (1.f / DIM) - mu * mu;
            float rs  = rsqrtf(var + LN_EPS);
            int byte0 = (rr * 256 + ln * 2) ^ ((rr & 7) << 4);
            int byte1 = (rr * 256 + (ln + 64) * 2) ^ ((rr & 7) << 4);
            *(__bf16*)((char*)Xs + byte0) = (__bf16)((x0 - mu) * rs * gc0 + bc0);
            *(__bf16*)((char*)Xs + byte1) = (__bf16)((x1 - mu) * rs * gc1 + bc1);
        }
    }
    __syncthreads();

    // GEMM1: T = relu(X @ W1 + b1); 8 col-tiles, one per wave, full K
    f32x16 acc1;
    #pragma unroll
    for (int i = 0; i < 16; ++i) acc1[i] = 0.f;
    #pragma unroll
    for (int kk = 0; kk < 8; ++kk) {
        int byte = (l31 * 256 + kk * 32 + hi * 16) ^ ((l31 & 7) << 4);
        bf16x8 a = *(const bf16x8*)((const char*)Xs + byte);
        acc1 = mfma_bf(a, *(const bf16x8*)(W1t + (size_t)(w * 32 + l31) * 128 + kk * 16 + hi * 8), acc1);
    }
    {
        int n = w * 32 + l31;
        float bb = b1[n];
        #pragma unroll
        for (int r = 0; r < 16; ++r) {
            int mm = (r & 3) + 8 * (r >> 2) + 4 * hi;
            float v = fmaxf(acc1[r] + bb, 0.f);
            int byte = (mm * 512 + n * 2) ^ ((mm & 7) << 4);
            *(__bf16*)((char*)Ts + byte) = (__bf16)v;
        }
    }
    __syncthreads();

    // GEMM2: C2 = T @ W2; split-K (K=256 -> 128 per wave)
    f32x16 acc2;
    #pragma unroll
    for (int i = 0; i < 16; ++i) acc2[i] = 0.f;
    #pragma unroll
    for (int kk = 0; kk < 8; ++kk) {
        int kkk = kh * 8 + kk;
        int byte = (l31 * 512 + kkk * 32 + hi * 16) ^ ((l31 & 7) << 4);
        bf16x8 a = *(const bf16x8*)((const char*)Ts + byte);
        acc2 = mfma_bf(a, *(const bf16x8*)(W2t + (size_t)(ct * 32 + l31) * 256 + kkk * 16 + hi * 8), acc2);
    }
    if (kh == 1) {
        #pragma unroll
        for (int r = 0; r < 16; ++r) accT[ct][lane][r] = acc2[r];
    }
    __syncthreads();
    if (kh == 0) {
        int n = ct * 32 + l31;
        float bb = b2[n];
        #pragma unroll
        for (int r = 0; r < 16; ++r) {
            int mm = (r & 3) + 8 * (r >> 2) + 4 * hi;
            int byteR = (mm * 256 + n * 2) ^ ((mm & 7) << 4);
            float resid = (float)*(const __bf16*)((const char*)Xs + byteR);
            vv[mm][n] = acc2[r] + accT[ct][lane][r] + bb + resid;
        }
    }
    __syncthreads();

    // LN2 -> out; 8 waves x 4 rows
    {
        const int ln = lane;
        float gc0 = g2[ln], bc0 = b2ln[ln], gc1 = g2[ln + 64], bc1 = b2ln[ln + 64];
        #pragma unroll
        for (int i = 0; i < 4; ++i) {
            int rr = w * 4 + i;
            float x0 = vv[rr][ln], x1 = vv[rr][ln + 64];
            float s = x0 + x1, s2 = x0 * x0 + x1 * x1;
            for (int off = 1; off < 64; off <<= 1) {
                s  += __shfl_xor(s,  off);
                s2 += __shfl_xor(s2, off);
            }
            float mu  = s * (1.f / DIM);
            float var = s2 * (1.f / DIM) - mu * mu;
            float rs  = rsqrtf(var + LN_EPS);
            size_t o = (size_t)(r0 + rr) * DIM;
            out[o + ln]      = (x0 - mu) * rs * gc0 + bc0;
            out[o + ln + 64] = (x1 - mu) * rs * gc1 + bc1;
        }
    }
}

extern "C" void kernel_launch(void* const* d_in, const int* in_sizes, int n_in,
                              void* d_out, int out_size, void* d_ws, size_t ws_size,
                              hipStream_t stream) {
    const int*   adj = (const int*)  d_in[0];
    const float* h   = (const float*)d_in[1];
    const float* Wq  = (const float*)d_in[2];
    const float* Wk  = (const float*)d_in[3];
    const float* Wv  = (const float*)d_in[4];
    const float* Wo  = (const float*)d_in[5];
    const float* bo  = (const float*)d_in[6];
    const float* g1  = (const float*)d_in[7];
    const float* b1l = (const float*)d_in[8];
    const float* W1  = (const float*)d_in[9];
    const float* b1  = (const float*)d_in[10];
    const float* W2  = (const float*)d_in[11];
    const float* b2  = (const float*)d_in[12];
    const float* g2  = (const float*)d_in[13];
    const float* b2l = (const float*)d_in[14];
    float* out = (float*)d_out;

    __bf16* AOb = (__bf16*)d_ws;                                   // 2MB
    unsigned int* adjbT = (unsigned int*)(AOb + (size_t)BN * DIM); // 512KB
    __bf16* Qb  = (__bf16*)(adjbT + (size_t)64 * 2048);            // 2MB
    __bf16* Kb  = Qb + (size_t)BN * DIM;                           // 2MB
    __bf16* Vt  = Kb + (size_t)BN * DIM;                           // 2MB
    __bf16* W1t = Vt + (size_t)BN * DIM;                           // 64KB
    __bf16* W2t = W1t + (size_t)DIM * FFN_;                        // 64KB
    __bf16* Wqt = W2t + (size_t)DIM * FFN_;                        // 32KB
    __bf16* Wkt = Wqt + (size_t)DIM * DIM;
    __bf16* Wvt = Wkt + (size_t)DIM * DIM;
    __bf16* Wot = Wvt + (size_t)DIM * DIM;
    __bf16* onesb = Wot + (size_t)DIM * DIM;                       // 2080 bf16

    hipLaunchKernelGGL(k_prep, dim3(16384 + 128), dim3(256), 0, stream,
                       adj, W1, W2, Wq, Wk, Wv, Wo,
                       adjbT, W1t, W2t, Wqt, Wkt, Wvt, Wot, onesb);
    hipLaunchKernelGGL(k_qkv, dim3(BN / 32), dim3(768), 0, stream,
                       h, Wqt, Wkt, Wvt, Qb, Kb, Vt);
    hipLaunchKernelGGL(k_attn, dim3(B_ * NH * (N_ / 128)), dim3(512), 0, stream,
                       Qb, Kb, Vt, adjbT, onesb, AOb);
    hipLaunchKernelGGL(k_tail, dim3(BN / 32), dim3(512), 0, stream,
                       AOb, h, Wot, bo, g1, b1l, W1t, b1, W2t, b2, g2, b2l, out);
}

// Round 20
// 53.160 us; speedup vs baseline: 1.7840x; 1.7840x over previous
//
#include <hip/hip_runtime.h>

#define B_   4
#define N_   2048
#define DIM  128
#define NH   8
#define HD   16
#define FFN_ 256
#define LN_EPS 1e-5f
#define BN   (B_*N_)
#define LOG2E 1.44269504f

#if __has_builtin(__builtin_amdgcn_exp2f)
#define EXP2(x) __builtin_amdgcn_exp2f(x)
#else
#define EXP2(x) exp2f(x)
#endif

typedef __bf16 bf16x8 __attribute__((ext_vector_type(8)));
typedef short  s16x8  __attribute__((ext_vector_type(8)));
typedef float  f32x16 __attribute__((ext_vector_type(16)));
typedef unsigned int u32x4 __attribute__((ext_vector_type(4)));

template<class T> struct as_short_vec { using type = s16x8; };

template <class T>
__device__ auto mfma_try(T a, T b, f32x16 c, int)
    -> decltype(__builtin_amdgcn_mfma_f32_32x32x16_bf16(a, b, c, 0, 0, 0)) {
  return __builtin_amdgcn_mfma_f32_32x32x16_bf16(a, b, c, 0, 0, 0);
}
template <class T>
__device__ f32x16 mfma_try(T a, T b, f32x16 c, long) {
  return __builtin_amdgcn_mfma_f32_32x32x16_bf16(
      __builtin_bit_cast(typename as_short_vec<T>::type, a),
      __builtin_bit_cast(typename as_short_vec<T>::type, b), c, 0, 0, 0);
}
__device__ __forceinline__ f32x16 mfma_bf(bf16x8 a, bf16x8 b, f32x16 c) {
  return mfma_try(a, b, c, 0);
}

// ---------------- fused prep: adj bits + weight cast + ones buffer ---------
// (r16 lesson: folding this into the qkv launch regressed — keep separate.)
__global__ __launch_bounds__(256) void k_prep(
    const int* __restrict__ adj,
    const float* __restrict__ W1, const float* __restrict__ W2,
    const float* __restrict__ Wq, const float* __restrict__ Wk,
    const float* __restrict__ Wv, const float* __restrict__ Wo,
    unsigned int* __restrict__ adjbT,
    __bf16* __restrict__ W1t, __bf16* __restrict__ W2t,
    __bf16* __restrict__ Wqt, __bf16* __restrict__ Wkt,
    __bf16* __restrict__ Wvt, __bf16* __restrict__ Wot,
    __bf16* __restrict__ onesb) {
    const int blk = blockIdx.x;
    const int tid = threadIdx.x;
    if (blk < 16384) {
        long long idx = (long long)blk * 256 + tid;
        int v = adj[idx] != 0;
        unsigned long long m = __ballot(v);
        if ((tid & 63) == 0) {
            int q  = (int)(idx >> 11);
            int kc = ((int)idx & 2047) >> 5;   // even; covers kc, kc+1
            adjbT[(size_t)kc * 2048 + q]       = (unsigned)m;
            adjbT[(size_t)(kc + 1) * 2048 + q] = (unsigned)(m >> 32);
        }
    } else {
        const int g = (blk - 16384) * 256 + tid;    // 32768 threads
        {
            int k = g >> 8, n = g & 255;
            W1t[(size_t)n * 128 + k] = (__bf16)W1[(size_t)k * 256 + n];
        }
        {
            int k = g >> 7, n = g & 127;
            W2t[(size_t)n * 256 + k] = (__bf16)W2[(size_t)k * 128 + n];
        }
        if (g < 16384) {
            int k = g >> 7, n = g & 127;
            size_t s = (size_t)k * 128 + n, d = (size_t)n * 128 + k;
            Wqt[d] = (__bf16)(Wq[s] * (0.25f * LOG2E));
            Wkt[d] = (__bf16)Wk[s];
            Wvt[d] = (__bf16)Wv[s];
            Wot[d] = (__bf16)Wo[s];
        }
        if (g < 2080) onesb[g] = (__bf16)1.0f;
    }
}

// ---------------- QKV projection, MFMA, 12 waves (3/SIMD) ----------------
__global__ __launch_bounds__(768) void k_qkv(
    const float* __restrict__ h,
    const __bf16* __restrict__ Wqt, const __bf16* __restrict__ Wkt,
    const __bf16* __restrict__ Wvt,
    __bf16* __restrict__ Qb, __bf16* __restrict__ Kb, __bf16* __restrict__ Vt) {
    const int r0   = blockIdx.x * 32;
    const int tid  = threadIdx.x;
    const int w    = tid >> 6;          // 0..11
    const int mat  = w >> 2;            // 0=Q 1=K 2=V
    const int ct   = w & 3;             // col-tile
    const int lane = tid & 63;
    const int l31  = lane & 31, hi = lane >> 5;

    __shared__ __bf16 Hs[32 * 128];   // XOR-swizzled: byte ^= (row&7)<<4

    if (tid < 512) {
        int row = tid >> 4, u = tid & 15;
        const float* src = h + (size_t)(r0 + row) * DIM + u * 8;
        float4 f0 = *(const float4*)src, f1 = *(const float4*)(src + 4);
        bf16x8 v;
        v[0] = (__bf16)f0.x; v[1] = (__bf16)f0.y; v[2] = (__bf16)f0.z; v[3] = (__bf16)f0.w;
        v[4] = (__bf16)f1.x; v[5] = (__bf16)f1.y; v[6] = (__bf16)f1.z; v[7] = (__bf16)f1.w;
        int byte = (row * 256 + u * 16) ^ ((row & 7) << 4);
        *(bf16x8*)((char*)Hs + byte) = v;
    }
    __syncthreads();

    const __bf16* Wsel = (mat == 0) ? Wqt : ((mat == 1) ? Wkt : Wvt);

    f32x16 a;
    #pragma unroll
    for (int i = 0; i < 16; ++i) a[i] = 0.f;
    #pragma unroll
    for (int kk = 0; kk < 8; ++kk) {
        int byte = (l31 * 256 + kk * 32 + hi * 16) ^ ((l31 & 7) << 4);
        bf16x8 af = *(const bf16x8*)((const char*)Hs + byte);
        a = mfma_bf(af, *(const bf16x8*)(Wsel + (size_t)(ct * 32 + l31) * 128 + kk * 16 + hi * 8), a);
    }

    const int n  = ct * 32 + l31;          // output col 0..127
    const int hh = n >> 4, d = n & 15;
    const int b  = r0 >> 11;
    const int nloc0 = r0 & (N_ - 1);
    if (mat < 2) {
        __bf16* dst = (mat == 0) ? Qb : Kb;
        const size_t qbase = (size_t)(b * NH + hh) * N_;
        #pragma unroll
        for (int r = 0; r < 16; ++r) {
            int mm = (r & 3) + 8 * (r >> 2) + 4 * hi;
            dst[(qbase + nloc0 + mm) * HD + d] = (__bf16)a[r];
        }
    } else {
        const size_t vbase = ((size_t)(b * NH + hh) * HD + d) * N_;
        #pragma unroll
        for (int r = 0; r < 16; ++r) {
            int mm   = (r & 3) + 8 * (r >> 2) + 4 * hi;
            int nloc = nloc0 + mm;
            int gg = (nloc >> 2) & 7;
            int ng = (gg & 4) | ((gg & 1) << 1) | ((gg >> 1) & 1);
            Vt[vbase + ((nloc & ~31) | (ng << 2) | (nloc & 3))] = (__bf16)a[r];
        }
    }
}

// ---------------- masked flash attention, MFMA, fixed-max softmax ----------
// r18 config (measured best 53.3 µs): 2 q-tiles (64 q-rows) per block — same
// K/V registers feed both tiles, halving K/V L2 traffic. Grid B*H*(N/64) =
// 1024 blocks x 512 thr; wave kq = 256-key eighth.
// r19 lesson: 4 q-tiles exceeded the 128-VGPR cap -> compiler spilled
// (VGPR=64, WRITE_SIZE 208MB, 77-84 µs). 2 tiles is this family's optimum.
// Do NOT pin launch_bounds min-waves above 4 (r5: VGPR=32 forced, acc spilled).
__global__ __launch_bounds__(512, 4) void k_attn(
    const __bf16* __restrict__ Qb, const __bf16* __restrict__ Kb,
    const __bf16* __restrict__ Vt, const unsigned int* __restrict__ adjbT,
    const __bf16* __restrict__ onesb,
    __bf16* __restrict__ AOb) {
    const int bid  = (blockIdx.x & 7) * 128 + (blockIdx.x >> 3);  // XCD chunking
    const int qt   = bid & 31;          // N/64 = 32 q-groups of 64 rows
    const int hh   = (bid >> 5) & 7;
    const int b    = bid >> 8;
    const int kq   = threadIdx.x >> 6;  // wave = K eighth
    const int lane = threadIdx.x & 63;
    const int l31  = lane & 31, hi = lane >> 5;
    const int q0    = qt * 64 + l31;
    const int q1    = q0 + 32;
    const int kbase = kq * 256;
    const int NT    = 8;                // 8 tiles of 32 keys per eighth

    __shared__ float accL[7][64][18];
    __shared__ uint2 lutM[16];

    if (threadIdx.x < 16) {
        unsigned v = threadIdx.x;
        lutM[v].x = ((v & 1u) ? 0xFFFFu : 0u) | ((v & 2u) ? 0xFFFF0000u : 0u);
        lutM[v].y = ((v & 4u) ? 0xFFFFu : 0u) | ((v & 8u) ? 0xFFFF0000u : 0u);
    }
    __syncthreads();

    const __bf16* Qh = Qb + (size_t)(b * NH + hh) * N_ * HD;
    const __bf16* Kp = Kb + (size_t)(b * NH + hh) * N_ * HD
                          + (size_t)(kbase + l31) * HD + hi * 8;
    const __bf16* Vp = ((l31 < 16)
        ? (Vt + ((size_t)(b * NH + hh) * HD + l31) * N_)
        : onesb) + kbase + hi * 8;
    const unsigned int* wp0 = adjbT + (size_t)(kq * NT) * 2048 + q0;
    const unsigned int* wp1 = wp0 + 32;

    bf16x8 qf0 = *(const bf16x8*)(Qh + (size_t)q0 * HD + hi * 8);
    bf16x8 qf1 = *(const bf16x8*)(Qh + (size_t)q1 * HD + hi * 8);

    f32x16 acc0, acc1;
    #pragma unroll
    for (int i = 0; i < 16; ++i) { acc0[i] = 0.f; acc1[i] = 0.f; }
    const f32x16 z = {};

    bf16x8 kf  = *(const bf16x8*)Kp;
    bf16x8 vfa = *(const bf16x8*)Vp;
    bf16x8 vfb = *(const bf16x8*)(Vp + 16);
    unsigned int w0 = wp0[0], w1 = wp1[0];

    #pragma unroll
    for (int t = 0; t < NT; ++t) {
        // prefetch tile t+1 (compile-time guard)
        bf16x8 kf_n = {}, vfa_n = {}, vfb_n = {};
        unsigned int w0_n = 0, w1_n = 0;
        if (t + 1 < NT) {
            kf_n  = *(const bf16x8*)(Kp + (t + 1) * 32 * HD);
            vfa_n = *(const bf16x8*)(Vp + (t + 1) * 32);
            vfb_n = *(const bf16x8*)(Vp + (t + 1) * 32 + 16);
            w0_n  = wp0[(size_t)(t + 1) * 2048];
            w1_n  = wp1[(size_t)(t + 1) * 2048];
        }

        // LUT mask reads issue early; consumed after QK-MFMA + exp chain
        const unsigned ws0 = w0 >> (4 * hi);
        const unsigned ws1 = w1 >> (4 * hi);
        uint2 a0 = lutM[ws0 & 15u];
        uint2 a1 = lutM[(ws0 >> 8) & 15u];
        uint2 a2 = lutM[(ws0 >> 16) & 15u];
        uint2 a3 = lutM[(ws0 >> 24) & 15u];
        uint2 b0 = lutM[ws1 & 15u];
        uint2 b1 = lutM[(ws1 >> 8) & 15u];
        uint2 b2 = lutM[(ws1 >> 16) & 15u];
        uint2 b3 = lutM[(ws1 >> 24) & 15u];

        // S^T[k][q] (log2-scaled): D: q = l31, k = (r&3)+8*(r>>2)+4*hi
        f32x16 st0 = mfma_bf(kf, qf0, z);
        f32x16 st1 = mfma_bf(kf, qf1, z);

        float p0[16], p1[16];
        #pragma unroll
        for (int r = 0; r < 16; ++r) { p0[r] = EXP2(st0[r]); p1[r] = EXP2(st1[r]); }
        bf16x8 pa0, pb0, pa1, pb1;
        #pragma unroll
        for (int r = 0; r < 8; ++r) {
            pa0[r] = (__bf16)p0[r]; pb0[r] = (__bf16)p0[r + 8];
            pa1[r] = (__bf16)p1[r]; pb1[r] = (__bf16)p1[r + 8];
        }

        u32x4 mA0 = {a0.x, a0.y, a1.x, a1.y};
        u32x4 mB0 = {a2.x, a2.y, a3.x, a3.y};
        u32x4 mA1 = {b0.x, b0.y, b1.x, b1.y};
        u32x4 mB1 = {b2.x, b2.y, b3.x, b3.y};
        pa0 = __builtin_bit_cast(bf16x8, __builtin_bit_cast(u32x4, pa0) & mA0);
        pb0 = __builtin_bit_cast(bf16x8, __builtin_bit_cast(u32x4, pb0) & mB0);
        pa1 = __builtin_bit_cast(bf16x8, __builtin_bit_cast(u32x4, pa1) & mA1);
        pb1 = __builtin_bit_cast(bf16x8, __builtin_bit_cast(u32x4, pb1) & mB1);

        // PV; A rows 16..31 read global ones -> acc[8] accumulates sum(p)
        acc0 = mfma_bf(vfa, pa0, acc0);
        acc0 = mfma_bf(vfb, pb0, acc0);
        acc1 = mfma_bf(vfa, pa1, acc1);
        acc1 = mfma_bf(vfb, pb1, acc1);

        if (t + 1 < NT) { kf = kf_n; vfa = vfa_n; vfb = vfb_n; w0 = w0_n; w1 = w1_n; }
    }

    // ---- 8-way split-K merge: pure sums, both q-tiles ----
    if (kq != 0) {
        #pragma unroll
        for (int r = 0; r < 9; ++r) {
            accL[kq - 1][lane][r]     = acc0[r];
            accL[kq - 1][lane][9 + r] = acc1[r];
        }
    }
    __syncthreads();
    if (kq == 0) {
        float tot0[9], tot1[9];
        #pragma unroll
        for (int r = 0; r < 9; ++r) {
            float v0 = acc0[r], v1 = acc1[r];
            #pragma unroll
            for (int i = 0; i < 7; ++i) {
                v0 += accL[i][lane][r];
                v1 += accL[i][lane][9 + r];
            }
            tot0[r] = v0; tot1[r] = v1;
        }
        float inv0 = 1.f / tot0[8], inv1 = 1.f / tot1[8];
        bf16x8 ov0, ov1;
        #pragma unroll
        for (int r = 0; r < 8; ++r) {
            ov0[r] = (__bf16)(tot0[r] * inv0);
            ov1[r] = (__bf16)(tot1[r] * inv1);
        }
        u32x4 ou0 = __builtin_bit_cast(u32x4, ov0);
        u32x4 ou1 = __builtin_bit_cast(u32x4, ov1);
        __bf16* op0 = AOb + ((size_t)(b * N_ + q0)) * DIM + hh * HD + 4 * hi;
        __bf16* op1 = AOb + ((size_t)(b * N_ + q1)) * DIM + hh * HD + 4 * hi;
        uint2 x0 = { ou0[0], ou0[1] }, x1 = { ou0[2], ou0[3] };
        uint2 y0 = { ou1[0], ou1[1] }, y1 = { ou1[2], ou1[3] };
        *(uint2*)op0       = x0;
        *(uint2*)(op0 + 8) = x1;
        *(uint2*)op1       = y0;
        *(uint2*)(op1 + 8) = y1;
    }
}

// ------- fused tail: Wo proj + residual + LN1 + FFN + residual + LN2 -------
// (unchanged from r15/r17: 512 thr, split-K Wo/GEMM2, per-wave GEMM1)
__global__ __launch_bounds__(512) void k_tail(
    const __bf16* __restrict__ AOb, const float* __restrict__ h,
    const __bf16* __restrict__ Wot, const float* __restrict__ bo,
    const float* __restrict__ g1, const float* __restrict__ b1ln,
    const __bf16* __restrict__ W1t, const float* __restrict__ b1,
    const __bf16* __restrict__ W2t, const float* __restrict__ b2,
    const float* __restrict__ g2, const float* __restrict__ b2ln,
    float* __restrict__ out) {
    const int r0   = blockIdx.x * 32;
    const int tid  = threadIdx.x;
    const int w    = tid >> 6;          // 0..7
    const int ct   = w & 3;
    const int kh   = w >> 2;
    const int lane = tid & 63;
    const int l31  = lane & 31, hi = lane >> 5;

    __shared__ __bf16 As[32 * 128];
    __shared__ __bf16 Xs[32 * 128];
    __shared__ __bf16 Ts[32 * 256];
    __shared__ float  vv[32][DIM];
    __shared__ float  accT[4][64][16];

    {
        int row = tid >> 4, u = tid & 15;
        bf16x8 v = *(const bf16x8*)(AOb + (size_t)(r0 + row) * DIM + u * 8);
        int byte = (row * 256 + u * 16) ^ ((row & 7) << 4);
        *(bf16x8*)((char*)As + byte) = v;
    }
    __syncthreads();

    // GEMM Wo: split-K (K=128 -> 64 per wave)
    f32x16 acc;
    #pragma unroll
    for (int i = 0; i < 16; ++i) acc[i] = 0.f;
    #pragma unroll
    for (int kk = 0; kk < 4; ++kk) {
        int kkk = kh * 4 + kk;
        int byte = (l31 * 256 + kkk * 32 + hi * 16) ^ ((l31 & 7) << 4);
        bf16x8 a = *(const bf16x8*)((const char*)As + byte);
        acc = mfma_bf(a, *(const bf16x8*)(Wot + (size_t)(ct * 32 + l31) * 128 + kkk * 16 + hi * 8), acc);
    }
    if (kh == 1) {
        #pragma unroll
        for (int r = 0; r < 16; ++r) accT[ct][lane][r] = acc[r];
    }
    __syncthreads();
    if (kh == 0) {
        int n = ct * 32 + l31;
        float bb = bo[n];
        #pragma unroll
        for (int r = 0; r < 16; ++r) {
            int mm = (r & 3) + 8 * (r >> 2) + 4 * hi;
            vv[mm][n] = acc[r] + accT[ct][lane][r] + bb + h[(size_t)(r0 + mm) * DIM + n];
        }
    }
    __syncthreads();

    // LN1 -> Xs (swizzled bf16); 8 waves x 4 rows
    {
        const int ln = lane;
        float gc0 = g1[ln], bc0 = b1ln[ln], gc1 = g1[ln + 64], bc1 = b1ln[ln + 64];
        #pragma unroll
        for (int i = 0; i < 4; ++i) {
            int rr = w * 4 + i;
            float x0 = vv[rr][ln], x1 = vv[rr][ln + 64];
            float s = x0 + x1, s2 = x0 * x0 + x1 * x1;
            for (int off = 1; off < 64; off <<= 1) {
                s  += __shfl_xor(s,  off);
                s2 += __shfl_xor(s2, off);
            }
            float mu  = s * (1.f / DIM);
            float var = s2 * (1.f / DIM) - mu * mu;
            float rs  = rsqrtf(var + LN_EPS);
            int byte0 = (rr * 256 + ln * 2) ^ ((rr & 7) << 4);
            int byte1 = (rr * 256 + (ln + 64) * 2) ^ ((rr & 7) << 4);
            *(__bf16*)((char*)Xs + byte0) = (__bf16)((x0 - mu) * rs * gc0 + bc0);
            *(__bf16*)((char*)Xs + byte1) = (__bf16)((x1 - mu) * rs * gc1 + bc1);
        }
    }
    __syncthreads();

    // GEMM1: T = relu(X @ W1 + b1); 8 col-tiles, one per wave, full K
    f32x16 acc1;
    #pragma unroll
    for (int i = 0; i < 16; ++i) acc1[i] = 0.f;
    #pragma unroll
    for (int kk = 0; kk < 8; ++kk) {
        int byte = (l31 * 256 + kk * 32 + hi * 16) ^ ((l31 & 7) << 4);
        bf16x8 a = *(const bf16x8*)((const char*)Xs + byte);
        acc1 = mfma_bf(a, *(const bf16x8*)(W1t + (size_t)(w * 32 + l31) * 128 + kk * 16 + hi * 8), acc1);
    }
    {
        int n = w * 32 + l31;
        float bb = b1[n];
        #pragma unroll
        for (int r = 0; r < 16; ++r) {
            int mm = (r & 3) + 8 * (r >> 2) + 4 * hi;
            float v = fmaxf(acc1[r] + bb, 0.f);
            int byte = (mm * 512 + n * 2) ^ ((mm & 7) << 4);
            *(__bf16*)((char*)Ts + byte) = (__bf16)v;
        }
    }
    __syncthreads();

    // GEMM2: C2 = T @ W2; split-K (K=256 -> 128 per wave)
    f32x16 acc2;
    #pragma unroll
    for (int i = 0; i < 16; ++i) acc2[i] = 0.f;
    #pragma unroll
    for (int kk = 0; kk < 8; ++kk) {
        int kkk = kh * 8 + kk;
        int byte = (l31 * 512 + kkk * 32 + hi * 16) ^ ((l31 & 7) << 4);
        bf16x8 a = *(const bf16x8*)((const char*)Ts + byte);
        acc2 = mfma_bf(a, *(const bf16x8*)(W2t + (size_t)(ct * 32 + l31) * 256 + kkk * 16 + hi * 8), acc2);
    }
    if (kh == 1) {
        #pragma unroll
        for (int r = 0; r < 16; ++r) accT[ct][lane][r] = acc2[r];
    }
    __syncthreads();
    if (kh == 0) {
        int n = ct * 32 + l31;
        float bb = b2[n];
        #pragma unroll
        for (int r = 0; r < 16; ++r) {
            int mm = (r & 3) + 8 * (r >> 2) + 4 * hi;
            int byteR = (mm * 256 + n * 2) ^ ((mm & 7) << 4);
            float resid = (float)*(const __bf16*)((const char*)Xs + byteR);
            vv[mm][n] = acc2[r] + accT[ct][lane][r] + bb + resid;
        }
    }
    __syncthreads();

    // LN2 -> out; 8 waves x 4 rows
    {
        const int ln = lane;
        float gc0 = g2[ln], bc0 = b2ln[ln], gc1 = g2[ln + 64], bc1 = b2ln[ln + 64];
        #pragma unroll
        for (int i = 0; i < 4; ++i) {
            int rr = w * 4 + i;
            float x0 = vv[rr][ln], x1 = vv[rr][ln + 64];
            float s = x0 + x1, s2 = x0 * x0 + x1 * x1;
            for (int off = 1; off < 64; off <<= 1) {
                s  += __shfl_xor(s,  off);
                s2 += __shfl_xor(s2, off);
            }
            float mu  = s * (1.f / DIM);
            float var = s2 * (1.f / DIM) - mu * mu;
            float rs  = rsqrtf(var + LN_EPS);
            size_t o = (size_t)(r0 + rr) * DIM;
            out[o + ln]      = (x0 - mu) * rs * gc0 + bc0;
            out[o + ln + 64] = (x1 - mu) * rs * gc1 + bc1;
        }
    }
}

extern "C" void kernel_launch(void* const* d_in, const int* in_sizes, int n_in,
                              void* d_out, int out_size, void* d_ws, size_t ws_size,
                              hipStream_t stream) {
    const int*   adj = (const int*)  d_in[0];
    const float* h   = (const float*)d_in[1];
    const float* Wq  = (const float*)d_in[2];
    const float* Wk  = (const float*)d_in[3];
    const float* Wv  = (const float*)d_in[4];
    const float* Wo  = (const float*)d_in[5];
    const float* bo  = (const float*)d_in[6];
    const float* g1  = (const float*)d_in[7];
    const float* b1l = (const float*)d_in[8];
    const float* W1  = (const float*)d_in[9];
    const float* b1  = (const float*)d_in[10];
    const float* W2  = (const float*)d_in[11];
    const float* b2  = (const float*)d_in[12];
    const float* g2  = (const float*)d_in[13];
    const float* b2l = (const float*)d_in[14];
    float* out = (float*)d_out;

    __bf16* AOb = (__bf16*)d_ws;                                   // 2MB
    unsigned int* adjbT = (unsigned int*)(AOb + (size_t)BN * DIM); // 512KB
    __bf16* Qb  = (__bf16*)(adjbT + (size_t)64 * 2048);            // 2MB
    __bf16* Kb  = Qb + (size_t)BN * DIM;                           // 2MB
    __bf16* Vt  = Kb + (size_t)BN * DIM;                           // 2MB
    __bf16* W1t = Vt + (size_t)BN * DIM;                           // 64KB
    __bf16* W2t = W1t + (size_t)DIM * FFN_;                        // 64KB
    __bf16* Wqt = W2t + (size_t)DIM * FFN_;                        // 32KB
    __bf16* Wkt = Wqt + (size_t)DIM * DIM;
    __bf16* Wvt = Wkt + (size_t)DIM * DIM;
    __bf16* Wot = Wvt + (size_t)DIM * DIM;
    __bf16* onesb = Wot + (size_t)DIM * DIM;                       // 2080 bf16

    hipLaunchKernelGGL(k_prep, dim3(16384 + 128), dim3(256), 0, stream,
                       adj, W1, W2, Wq, Wk, Wv, Wo,
                       adjbT, W1t, W2t, Wqt, Wkt, Wvt, Wot, onesb);
    hipLaunchKernelGGL(k_qkv, dim3(BN / 32), dim3(768), 0, stream,
                       h, Wqt, Wkt, Wvt, Qb, Kb, Vt);
    hipLaunchKernelGGL(k_attn, dim3(B_ * NH * (N_ / 64)), dim3(512), 0, stream,
                       Qb, Kb, Vt, adjbT, onesb, AOb);
    hipLaunchKernelGGL(k_tail, dim3(BN / 32), dim3(512), 0, stream,
                       AOb, h, Wot, bo, g1, b1l, W1t, b1, W2t, b2, g2, b2l, out);
}